// Round 1
// baseline (177.618 us; speedup 1.0000x reference)
//
#include <hip/hip_runtime.h>
#include <stdint.h>

#define BB   16
#define NGT  128
#define LL   8400
#define CC   80
#define KTOP 13
#define FEPS 1e-9f

__device__ __forceinline__ float iou_f(float4 g, float4 p) {
    float ix0 = fmaxf(g.x, p.x);
    float iy0 = fmaxf(g.y, p.y);
    float ix1 = fminf(g.z, p.z);
    float iy1 = fminf(g.w, p.w);
    float ow = fmaxf(ix1 - ix0, 0.0f);
    float oh = fmaxf(iy1 - iy0, 0.0f);
    float ov = ow * oh;
    float a1 = fmaxf(g.z - g.x, 0.0f) * fmaxf(g.w - g.y, 0.0f);
    float a2 = fmaxf(p.z - p.x, 0.0f) * fmaxf(p.w - p.y, 0.0f);
    return ov / (a1 + a2 - ov + FEPS);
}

// ---------------- Kernel A: exact top-13 per (b, gt) row -------------------
// One wave (64 lanes) per row. Key = (val_bits << 32) | ~idx  -> max-order
// equals (value desc, index asc), matching jax.lax.top_k tie semantics.
__global__ __launch_bounds__(64) void topk_kernel(
    const float*  __restrict__ pred_scores,   // B,L,C
    const float4* __restrict__ pred_bboxes,   // B,L
    const float2* __restrict__ anchors,       // L
    const int*    __restrict__ gt_labels,     // B,n
    const float4* __restrict__ gt_bboxes,     // B,n
    int*          __restrict__ topk_idx)      // B,n,KTOP
{
    int row  = blockIdx.x;           // b*NGT + i
    int b    = row >> 7;
    int lane = threadIdx.x;

    float4 g   = gt_bboxes[row];
    int label  = gt_labels[row];
    const float*  sc = pred_scores + (size_t)b * LL * CC + label;
    const float4* pb = pred_bboxes + (size_t)b * LL;

    unsigned long long keys[KTOP];
#pragma unroll
    for (int k = 0; k < KTOP; ++k) keys[k] = 0ull;

    for (int j = lane; j < LL; j += 64) {
        float4 p = pb[j];
        float iou = iou_f(g, p);
        float2 ap = anchors[j];
        float l  = ap.x - g.x;
        float t  = ap.y - g.y;
        float r  = g.z - ap.x;
        float bt = g.w - ap.y;
        float d  = fminf(fminf(l, t), fminf(r, bt));
        float metric = 0.0f;
        if (d > FEPS) {
            float s  = sc[(size_t)j * CC];
            float i2 = iou * iou;
            metric = s * (i2 * i2 * i2);
        }
        unsigned long long key =
            ((unsigned long long)__float_as_uint(metric) << 32) | (unsigned)(~(unsigned)j);
        if (key > keys[KTOP - 1]) {
            keys[KTOP - 1] = key;
#pragma unroll
            for (int k = KTOP - 1; k > 0; --k) {
                unsigned long long a = keys[k - 1], c = keys[k];
                keys[k - 1] = (c > a) ? c : a;
                keys[k]     = (c > a) ? a : c;
            }
        }
    }

    // 13-round wave merge: each round take the global max head; owner pops.
    for (int r = 0; r < KTOP; ++r) {
        unsigned long long head = keys[0];
        unsigned long long m = head;
#pragma unroll
        for (int off = 1; off < 64; off <<= 1) {
            unsigned long long o = __shfl_xor(m, off, 64);
            if (o > m) m = o;
        }
        if (head == m) {      // unique (indices distinct)
#pragma unroll
            for (int k = 0; k < KTOP - 1; ++k) keys[k] = keys[k + 1];
            keys[KTOP - 1] = 0ull;
        }
        if (lane == 0)
            topk_idx[row * KTOP + r] = (int)(~(unsigned)(m & 0xFFFFFFFFull));
    }
}

// ---------------- Kernel B: scatter claims ---------------------------------
__global__ __launch_bounds__(256) void claim_kernel(
    const float2* __restrict__ anchors,
    const float4* __restrict__ gt_bboxes,
    const int*    __restrict__ topk_idx,
    int* __restrict__ claim_count,
    int* __restrict__ claimant)
{
    int t = blockIdx.x * 256 + threadIdx.x;
    if (t >= BB * NGT * KTOP) return;
    int row = t / KTOP;          // b*NGT + i
    int b   = row >> 7;
    int i   = row & (NGT - 1);
    int j   = topk_idx[t];
    float4 g  = gt_bboxes[row];
    float2 ap = anchors[j];
    float l  = ap.x - g.x;
    float tt = ap.y - g.y;
    float r  = g.z - ap.x;
    float bt = g.w - ap.y;
    float d  = fminf(fminf(l, tt), fminf(r, bt));
    if (d > FEPS) {
        atomicAdd(claim_count + b * LL + j, 1);
        atomicMax(claimant + b * LL + j, i);
    }
}

// ---------------- Kernel C: resolve contested + per-GT maxes ---------------
__global__ __launch_bounds__(256) void resolve_kernel(
    const float*  __restrict__ pred_scores,
    const float4* __restrict__ pred_bboxes,
    const int*    __restrict__ gt_labels,
    const float4* __restrict__ gt_bboxes,
    const int*    __restrict__ claim_count,
    const int*    __restrict__ claimant,
    int*      __restrict__ assigned_gt,
    float*    __restrict__ align_anchor,
    unsigned* __restrict__ max_metric,
    unsigned* __restrict__ max_iou)
{
    int b = blockIdx.y;
    int j = blockIdx.x * 256 + threadIdx.x;

    __shared__ float4 gbox[NGT];
    __shared__ int    glab[NGT];
    if (threadIdx.x < NGT) {
        gbox[threadIdx.x] = gt_bboxes[b * NGT + threadIdx.x];
        glab[threadIdx.x] = gt_labels[b * NGT + threadIdx.x];
    }
    __syncthreads();
    if (j >= LL) return;

    int idx = b * LL + j;
    int cnt = claim_count[idx];
    int g = -1;
    float4 p = pred_bboxes[(size_t)b * LL + j];

    if (cnt == 1) {
        g = claimant[idx];
    } else if (cnt > 1) {
        // argmax_i iou over ALL gts, first-max tie-break (strict >)
        float best = -1.0f;
        int   bi   = 0;
        for (int i = 0; i < NGT; ++i) {
            float iou = iou_f(gbox[i], p);
            if (iou > best) { best = iou; bi = i; }
        }
        g = bi;
    }
    assigned_gt[idx] = g;

    if (g >= 0) {
        float iou = iou_f(gbox[g], p);
        float s   = pred_scores[((size_t)b * LL + j) * CC + glab[g]];
        float i2  = iou * iou;
        float al  = s * (i2 * i2 * i2);
        align_anchor[idx] = al;
        atomicMax(max_metric + b * NGT + g, __float_as_uint(al));
        atomicMax(max_iou    + b * NGT + g, __float_as_uint(iou));
    }
}

// ---------------- Kernel E: outputs ----------------------------------------
__global__ __launch_bounds__(256) void output_kernel(
    const float4* __restrict__ gt_bboxes,
    const int*    __restrict__ gt_labels,
    const int*    __restrict__ assigned_gt,
    const float*  __restrict__ align_anchor,
    const unsigned* __restrict__ max_metric,
    const unsigned* __restrict__ max_iou,
    float*  __restrict__ out_labels,
    float4* __restrict__ out_bboxes,
    float*  __restrict__ out_scores)
{
    int t = blockIdx.x * 256 + threadIdx.x;
    if (t >= BB * LL) return;
    int b = t / LL;
    int g = assigned_gt[t];
    int label;
    float4 bb;
    if (g >= 0) {
        label = gt_labels[b * NGT + g];
        bb    = gt_bboxes[b * NGT + g];
        float mm = __uint_as_float(max_metric[b * NGT + g]);
        float mi = __uint_as_float(max_iou[b * NGT + g]);
        float f  = align_anchor[t] / (mm + FEPS) * mi;
        out_scores[(size_t)t * CC + label] = f;
    } else {
        label = CC;                       // 80 = NUM_CLASSES
        bb    = gt_bboxes[b * NGT + 0];   // argmax of all-zero mask -> gt 0
    }
    out_labels[t] = (float)label;
    out_bboxes[t] = bb;
}

extern "C" void kernel_launch(void* const* d_in, const int* in_sizes, int n_in,
                              void* d_out, int out_size, void* d_ws, size_t ws_size,
                              hipStream_t stream)
{
    const float*  pred_scores = (const float*)d_in[0];
    const float4* pred_bboxes = (const float4*)d_in[1];
    const float2* anchors     = (const float2*)d_in[2];
    const int*    gt_labels   = (const int*)d_in[3];
    const float4* gt_bboxes   = (const float4*)d_in[4];
    // d_in[5] = pad_gt_mask (all ones by construction)

    char* w = (char*)d_ws;
    // zeroed region (one memset): claim_count, claimant, max_metric, max_iou
    int*      claim_count  = (int*)(w);                 // B*L      = 537600 B
    int*      claimant     = (int*)(w + 537600);        // B*L      = 537600 B
    unsigned* max_metric   = (unsigned*)(w + 1075200);  // B*NGT    =   8192 B
    unsigned* max_iou      = (unsigned*)(w + 1083392);  // B*NGT    =   8192 B
    // non-zeroed (fully overwritten or guarded):
    int*      topk_idx     = (int*)(w + 1091584);       // B*NGT*13 = 106496 B
    int*      assigned_gt  = (int*)(w + 1198080);       // B*L      = 537600 B
    float*    align_anchor = (float*)(w + 1735680);     // B*L      = 537600 B

    float*  out        = (float*)d_out;
    float*  out_labels = out;                                   // B*L
    float4* out_bboxes = (float4*)(out + (size_t)BB * LL);      // B*L*4
    float*  out_scores = out + (size_t)BB * LL * 5;             // B*L*80

    hipMemsetAsync(w, 0, 1091584, stream);
    hipMemsetAsync(out_scores, 0, (size_t)BB * LL * CC * sizeof(float), stream);

    topk_kernel<<<BB * NGT, 64, 0, stream>>>(
        pred_scores, pred_bboxes, anchors, gt_labels, gt_bboxes, topk_idx);

    claim_kernel<<<(BB * NGT * KTOP + 255) / 256, 256, 0, stream>>>(
        anchors, gt_bboxes, topk_idx, claim_count, claimant);

    dim3 gridC((LL + 255) / 256, BB);
    resolve_kernel<<<gridC, 256, 0, stream>>>(
        pred_scores, pred_bboxes, gt_labels, gt_bboxes,
        claim_count, claimant, assigned_gt, align_anchor, max_metric, max_iou);

    output_kernel<<<(BB * LL + 255) / 256, 256, 0, stream>>>(
        gt_bboxes, gt_labels, assigned_gt, align_anchor, max_metric, max_iou,
        out_labels, out_bboxes, out_scores);
}

// Round 2
// 138.818 us; speedup vs baseline: 1.2795x; 1.2795x over previous
//
#include <hip/hip_runtime.h>
#include <stdint.h>

#define BB   16
#define NGT  128
#define LL   8400
#define CC   80
#define KTOP 13
#define FEPS 1e-9f

__device__ __forceinline__ float iou_f(float4 g, float4 p) {
    float ix0 = fmaxf(g.x, p.x);
    float iy0 = fmaxf(g.y, p.y);
    float ix1 = fminf(g.z, p.z);
    float iy1 = fminf(g.w, p.w);
    float ow = fmaxf(ix1 - ix0, 0.0f);
    float oh = fmaxf(iy1 - iy0, 0.0f);
    float ov = ow * oh;
    float a1 = fmaxf(g.z - g.x, 0.0f) * fmaxf(g.w - g.y, 0.0f);
    float a2 = fmaxf(p.z - p.x, 0.0f) * fmaxf(p.w - p.y, 0.0f);
    return ov / (a1 + a2 - ov + FEPS);
}

// ---------------- Kernel A: exact top-13 per (b, gt) row -------------------
// 256 threads (4 waves) per row. Key = (val_bits << 32) | ~idx -> max-order
// equals (value desc, index asc) = jax.lax.top_k tie semantics.
// Fast path: anchor outside gt box => metric is EXACTLY 0.0 in the reference
// (alignment * is_in_gts), so key = ~j needs no IoU / bbox / score load.
__global__ __launch_bounds__(256) void topk_kernel(
    const float*  __restrict__ pred_scores,   // B,L,C
    const float4* __restrict__ pred_bboxes,   // B,L
    const float2* __restrict__ anchors,       // L
    const int*    __restrict__ gt_labels,     // B,n
    const float4* __restrict__ gt_bboxes,     // B,n
    int*          __restrict__ topk_idx)      // B,n,KTOP
{
    int row  = blockIdx.x;           // b*NGT + i
    int b    = row >> 7;
    int tid  = threadIdx.x;
    int wave = tid >> 6;
    int lane = tid & 63;

    float4 g   = gt_bboxes[row];
    int label  = gt_labels[row];
    const float*  sc = pred_scores + (size_t)b * LL * CC + label;
    const float4* pb = pred_bboxes + (size_t)b * LL;

    unsigned long long keys[KTOP];
#pragma unroll
    for (int k = 0; k < KTOP; ++k) keys[k] = 0ull;

    for (int j = tid; j < LL; j += 256) {
        float2 ap = anchors[j];
        float l  = ap.x - g.x;
        float t  = ap.y - g.y;
        float r  = g.z - ap.x;
        float bt = g.w - ap.y;
        float d  = fminf(fminf(l, t), fminf(r, bt));
        unsigned long long key = (unsigned)(~(unsigned)j);
        if (d > FEPS) {
            float4 p  = pb[j];
            float iou = iou_f(g, p);
            float s   = sc[(size_t)j * CC];
            float i2  = iou * iou;
            float metric = s * (i2 * i2 * i2);
            key |= ((unsigned long long)__float_as_uint(metric) << 32);
        }
        if (key > keys[KTOP - 1]) {
            keys[KTOP - 1] = key;
#pragma unroll
            for (int k = KTOP - 1; k > 0; --k) {
                unsigned long long a = keys[k - 1], c = keys[k];
                keys[k - 1] = (c > a) ? c : a;
                keys[k]     = (c > a) ? a : c;
            }
        }
    }

    // Stage 1: per-wave top-13 via 13 rounds of wave-argmax + owner-pop.
    __shared__ unsigned long long wkeys[4 * KTOP];
    for (int r = 0; r < KTOP; ++r) {
        unsigned long long head = keys[0];
        unsigned long long m = head;
#pragma unroll
        for (int off = 1; off < 64; off <<= 1) {
            unsigned long long o = __shfl_xor(m, off, 64);
            if (o > m) m = o;
        }
        if (head == m && m != 0ull) {   // unique owner (indices distinct)
#pragma unroll
            for (int k = 0; k < KTOP - 1; ++k) keys[k] = keys[k + 1];
            keys[KTOP - 1] = 0ull;
        }
        if (lane == 0) wkeys[wave * KTOP + r] = m;
    }
    __syncthreads();

    // Stage 2: wave 0 merges the 4 sorted 13-lists (52 keys, one per lane).
    if (wave == 0) {
        unsigned long long k1 = (lane < 4 * KTOP) ? wkeys[lane] : 0ull;
        for (int r = 0; r < KTOP; ++r) {
            unsigned long long m = k1;
#pragma unroll
            for (int off = 1; off < 64; off <<= 1) {
                unsigned long long o = __shfl_xor(m, off, 64);
                if (o > m) m = o;
            }
            if (k1 == m && m != 0ull) k1 = 0ull;   // pop
            if (lane == 0)
                topk_idx[row * KTOP + r] = (int)(~(unsigned)(m & 0xFFFFFFFFull));
        }
    }
}

// ---------------- Kernel B: scatter claims ---------------------------------
__global__ __launch_bounds__(256) void claim_kernel(
    const float2* __restrict__ anchors,
    const float4* __restrict__ gt_bboxes,
    const int*    __restrict__ topk_idx,
    int* __restrict__ claim_count,
    int* __restrict__ claimant)
{
    int t = blockIdx.x * 256 + threadIdx.x;
    if (t >= BB * NGT * KTOP) return;
    int row = t / KTOP;          // b*NGT + i
    int b   = row >> 7;
    int i   = row & (NGT - 1);
    int j   = topk_idx[t];
    float4 g  = gt_bboxes[row];
    float2 ap = anchors[j];
    float l  = ap.x - g.x;
    float tt = ap.y - g.y;
    float r  = g.z - ap.x;
    float bt = g.w - ap.y;
    float d  = fminf(fminf(l, tt), fminf(r, bt));
    if (d > FEPS) {
        atomicAdd(claim_count + b * LL + j, 1);
        atomicMax(claimant + b * LL + j, i);
    }
}

// ---------------- Kernel C: resolve contested + per-GT maxes ---------------
__global__ __launch_bounds__(256) void resolve_kernel(
    const float*  __restrict__ pred_scores,
    const float4* __restrict__ pred_bboxes,
    const int*    __restrict__ gt_labels,
    const float4* __restrict__ gt_bboxes,
    const int*    __restrict__ claim_count,
    const int*    __restrict__ claimant,
    int*      __restrict__ assigned_gt,
    float*    __restrict__ align_anchor,
    unsigned* __restrict__ max_metric,
    unsigned* __restrict__ max_iou)
{
    int b = blockIdx.y;
    int j = blockIdx.x * 256 + threadIdx.x;

    __shared__ float4 gbox[NGT];
    __shared__ int    glab[NGT];
    if (threadIdx.x < NGT) {
        gbox[threadIdx.x] = gt_bboxes[b * NGT + threadIdx.x];
        glab[threadIdx.x] = gt_labels[b * NGT + threadIdx.x];
    }
    __syncthreads();
    if (j >= LL) return;

    int idx = b * LL + j;
    int cnt = claim_count[idx];
    int g = -1;
    float4 p = pred_bboxes[(size_t)b * LL + j];

    if (cnt == 1) {
        g = claimant[idx];
    } else if (cnt > 1) {
        // argmax_i iou over ALL gts, first-max tie-break (strict >)
        float best = -1.0f;
        int   bi   = 0;
        for (int i = 0; i < NGT; ++i) {
            float iou = iou_f(gbox[i], p);
            if (iou > best) { best = iou; bi = i; }
        }
        g = bi;
    }
    assigned_gt[idx] = g;

    if (g >= 0) {
        float iou = iou_f(gbox[g], p);
        float s   = pred_scores[((size_t)b * LL + j) * CC + glab[g]];
        float i2  = iou * iou;
        float al  = s * (i2 * i2 * i2);
        align_anchor[idx] = al;
        atomicMax(max_metric + b * NGT + g, __float_as_uint(al));
        atomicMax(max_iou    + b * NGT + g, __float_as_uint(iou));
    }
}

// ---------------- Kernel E: outputs ----------------------------------------
__global__ __launch_bounds__(256) void output_kernel(
    const float4* __restrict__ gt_bboxes,
    const int*    __restrict__ gt_labels,
    const int*    __restrict__ assigned_gt,
    const float*  __restrict__ align_anchor,
    const unsigned* __restrict__ max_metric,
    const unsigned* __restrict__ max_iou,
    float*  __restrict__ out_labels,
    float4* __restrict__ out_bboxes,
    float*  __restrict__ out_scores)
{
    int t = blockIdx.x * 256 + threadIdx.x;
    if (t >= BB * LL) return;
    int b = t / LL;
    int g = assigned_gt[t];
    int label;
    float4 bb;
    if (g >= 0) {
        label = gt_labels[b * NGT + g];
        bb    = gt_bboxes[b * NGT + g];
        float mm = __uint_as_float(max_metric[b * NGT + g]);
        float mi = __uint_as_float(max_iou[b * NGT + g]);
        float f  = align_anchor[t] / (mm + FEPS) * mi;
        out_scores[(size_t)t * CC + label] = f;
    } else {
        label = CC;                       // 80 = NUM_CLASSES
        bb    = gt_bboxes[b * NGT + 0];   // argmax of all-zero mask -> gt 0
    }
    out_labels[t] = (float)label;
    out_bboxes[t] = bb;
}

extern "C" void kernel_launch(void* const* d_in, const int* in_sizes, int n_in,
                              void* d_out, int out_size, void* d_ws, size_t ws_size,
                              hipStream_t stream)
{
    const float*  pred_scores = (const float*)d_in[0];
    const float4* pred_bboxes = (const float4*)d_in[1];
    const float2* anchors     = (const float2*)d_in[2];
    const int*    gt_labels   = (const int*)d_in[3];
    const float4* gt_bboxes   = (const float4*)d_in[4];
    // d_in[5] = pad_gt_mask (all ones by construction)

    char* w = (char*)d_ws;
    // zeroed region (one memset): claim_count, claimant, max_metric, max_iou
    int*      claim_count  = (int*)(w);                 // B*L      = 537600 B
    int*      claimant     = (int*)(w + 537600);        // B*L      = 537600 B
    unsigned* max_metric   = (unsigned*)(w + 1075200);  // B*NGT    =   8192 B
    unsigned* max_iou      = (unsigned*)(w + 1083392);  // B*NGT    =   8192 B
    // non-zeroed (fully overwritten or guarded):
    int*      topk_idx     = (int*)(w + 1091584);       // B*NGT*13 = 106496 B
    int*      assigned_gt  = (int*)(w + 1198080);       // B*L      = 537600 B
    float*    align_anchor = (float*)(w + 1735680);     // B*L      = 537600 B

    float*  out        = (float*)d_out;
    float*  out_labels = out;                                   // B*L
    float4* out_bboxes = (float4*)(out + (size_t)BB * LL);      // B*L*4
    float*  out_scores = out + (size_t)BB * LL * 5;             // B*L*80

    hipMemsetAsync(w, 0, 1091584, stream);
    hipMemsetAsync(out_scores, 0, (size_t)BB * LL * CC * sizeof(float), stream);

    topk_kernel<<<BB * NGT, 256, 0, stream>>>(
        pred_scores, pred_bboxes, anchors, gt_labels, gt_bboxes, topk_idx);

    claim_kernel<<<(BB * NGT * KTOP + 255) / 256, 256, 0, stream>>>(
        anchors, gt_bboxes, topk_idx, claim_count, claimant);

    dim3 gridC((LL + 255) / 256, BB);
    resolve_kernel<<<gridC, 256, 0, stream>>>(
        pred_scores, pred_bboxes, gt_labels, gt_bboxes,
        claim_count, claimant, assigned_gt, align_anchor, max_metric, max_iou);

    output_kernel<<<(BB * LL + 255) / 256, 256, 0, stream>>>(
        gt_bboxes, gt_labels, assigned_gt, align_anchor, max_metric, max_iou,
        out_labels, out_bboxes, out_scores);
}

// Round 3
// 114.002 us; speedup vs baseline: 1.5580x; 1.2177x over previous
//
#include <hip/hip_runtime.h>
#include <stdint.h>

#define BB   16
#define NGT  128
#define LL   8400
#define CC   80
#define KTOP 13
#define CAP  2048
#define FEPS 1e-9f

__device__ __forceinline__ float iou_f(float4 g, float4 p) {
    float ix0 = fmaxf(g.x, p.x);
    float iy0 = fmaxf(g.y, p.y);
    float ix1 = fminf(g.z, p.z);
    float iy1 = fminf(g.w, p.w);
    float ow = fmaxf(ix1 - ix0, 0.0f);
    float oh = fmaxf(iy1 - iy0, 0.0f);
    float ov = ow * oh;
    float a1 = fmaxf(g.z - g.x, 0.0f) * fmaxf(g.w - g.y, 0.0f);
    float a2 = fmaxf(p.z - p.x, 0.0f) * fmaxf(p.w - p.y, 0.0f);
    return ov / (a1 + a2 - ov + FEPS);
}

// --------- Kernel A: exact top-13 per (b,gt) row + fused claim -------------
// Phase 1: compact in-box anchor indices to LDS (pure VALU, no gathers).
// Phase 2: gathers + per-lane top-13 only over the ~1% inside pairs.
// Key = (metric_bits << 32) | ~j  -> max-order == (value desc, index asc),
// exactly jax.lax.top_k tie semantics. Rows with <13 positive metrics get
// their zero-fill slots from global index order: those fills provably have
// j < 26, covered by virtual zero keys for outside-box j < 32.
__global__ __launch_bounds__(256) void topk_kernel(
    const float*  __restrict__ pred_scores,   // B,L,C
    const float4* __restrict__ pred_bboxes,   // B,L
    const float2* __restrict__ anchors,       // L
    const int*    __restrict__ gt_labels,     // B,n
    const float4* __restrict__ gt_bboxes,     // B,n
    int* __restrict__ claim_count,            // B,L (zeroed)
    int* __restrict__ claimant)               // B,L (zeroed)
{
    int row  = blockIdx.x;           // b*NGT + i
    int b    = row >> 7;
    int tid  = threadIdx.x;
    int wave = tid >> 6;
    int lane = tid & 63;

    float4 g   = gt_bboxes[row];
    int label  = gt_labels[row];
    const float*  sc = pred_scores + (size_t)b * LL * CC + label;
    const float4* pb = pred_bboxes + (size_t)b * LL;

    __shared__ int s_cnt;
    __shared__ int s_list[CAP];
    __shared__ unsigned long long wkeys[4 * KTOP];
    __shared__ int s_pick[KTOP];
    if (tid == 0) s_cnt = 0;
    __syncthreads();

    // ---- Phase 1: in-box compaction (wave-aggregated append) ----
    for (int j = tid; j < LL; j += 256) {
        float2 ap = anchors[j];
        float d = fminf(fminf(ap.x - g.x, ap.y - g.y),
                        fminf(g.z - ap.x, g.w - ap.y));
        bool inside = d > FEPS;
        unsigned long long mask = __ballot(inside);
        if (mask) {
            int leader = __ffsll((unsigned long long)mask) - 1;
            int base = 0;
            if (lane == leader) base = atomicAdd(&s_cnt, __popcll(mask));
            base = __shfl(base, leader, 64);
            if (inside) {
                int slot = base + __popcll(mask & ((1ull << lane) - 1ull));
                if (slot < CAP) s_list[slot] = j;
            }
        }
    }
    __syncthreads();
    int c = s_cnt; if (c > CAP) c = CAP;

    // ---- Phase 2: per-lane top-13 over candidates (+ virtual zeros) ----
    unsigned long long keys[KTOP];
#pragma unroll
    for (int k = 0; k < KTOP; ++k) keys[k] = 0ull;

    if (tid < 32) {   // virtual zero-metric keys for outside-box j<32
        float2 ap = anchors[tid];
        float d = fminf(fminf(ap.x - g.x, ap.y - g.y),
                        fminf(g.z - ap.x, g.w - ap.y));
        if (!(d > FEPS)) keys[0] = (unsigned)(~(unsigned)tid);
    }

    for (int t = tid; t < c; t += 256) {
        int j = s_list[t];
        float4 p  = pb[j];
        float iou = iou_f(g, p);
        float s   = sc[(size_t)j * CC];
        float i2  = iou * iou;
        float metric = s * (i2 * i2 * i2);
        unsigned long long key =
            ((unsigned long long)__float_as_uint(metric) << 32) | (unsigned)(~(unsigned)j);
        if (key > keys[KTOP - 1]) {
            keys[KTOP - 1] = key;
#pragma unroll
            for (int k = KTOP - 1; k > 0; --k) {
                unsigned long long a = keys[k - 1], cc2 = keys[k];
                keys[k - 1] = (cc2 > a) ? cc2 : a;
                keys[k]     = (cc2 > a) ? a : cc2;
            }
        }
    }

    // Stage 1: per-wave top-13 (13 rounds of wave-argmax + owner-pop).
    for (int r = 0; r < KTOP; ++r) {
        unsigned long long head = keys[0];
        unsigned long long m = head;
#pragma unroll
        for (int off = 1; off < 64; off <<= 1) {
            unsigned long long o = __shfl_xor(m, off, 64);
            if (o > m) m = o;
        }
        if (head == m && m != 0ull) {   // unique owner (keys distinct)
#pragma unroll
            for (int k = 0; k < KTOP - 1; ++k) keys[k] = keys[k + 1];
            keys[KTOP - 1] = 0ull;
        }
        if (lane == 0) wkeys[wave * KTOP + r] = m;
    }
    __syncthreads();

    // Stage 2: wave 0 merges the 4 sorted 13-lists (52 keys, one per lane).
    if (wave == 0) {
        unsigned long long k1 = (lane < 4 * KTOP) ? wkeys[lane] : 0ull;
        for (int r = 0; r < KTOP; ++r) {
            unsigned long long m = k1;
#pragma unroll
            for (int off = 1; off < 64; off <<= 1) {
                unsigned long long o = __shfl_xor(m, off, 64);
                if (o > m) m = o;
            }
            if (k1 == m && m != 0ull) k1 = 0ull;   // pop
            if (lane == 0) s_pick[r] = (int)(~(unsigned)(m & 0xFFFFFFFFull));
        }
    }
    __syncthreads();

    // Fused claim: recheck in-box per pick, scatter atomics.
    if (tid < KTOP) {
        int j = s_pick[tid];
        float2 ap = anchors[j];
        float d = fminf(fminf(ap.x - g.x, ap.y - g.y),
                        fminf(g.z - ap.x, g.w - ap.y));
        if (d > FEPS) {
            atomicAdd(claim_count + b * LL + j, 1);
            atomicMax(claimant + b * LL + j, row & (NGT - 1));
        }
    }
}

// ---------------- Kernel C: resolve contested + per-GT maxes ---------------
__global__ __launch_bounds__(256) void resolve_kernel(
    const float*  __restrict__ pred_scores,
    const float4* __restrict__ pred_bboxes,
    const int*    __restrict__ gt_labels,
    const float4* __restrict__ gt_bboxes,
    const int*    __restrict__ claim_count,
    const int*    __restrict__ claimant,
    int*      __restrict__ assigned_gt,
    float*    __restrict__ align_anchor,
    unsigned* __restrict__ max_metric,
    unsigned* __restrict__ max_iou)
{
    int b = blockIdx.y;
    int j = blockIdx.x * 256 + threadIdx.x;

    __shared__ float4 gbox[NGT];
    __shared__ int    glab[NGT];
    if (threadIdx.x < NGT) {
        gbox[threadIdx.x] = gt_bboxes[b * NGT + threadIdx.x];
        glab[threadIdx.x] = gt_labels[b * NGT + threadIdx.x];
    }
    __syncthreads();
    if (j >= LL) return;

    int idx = b * LL + j;
    int cnt = claim_count[idx];
    int g = -1;
    float4 p = pred_bboxes[(size_t)b * LL + j];

    if (cnt == 1) {
        g = claimant[idx];
    } else if (cnt > 1) {
        // argmax_i iou over ALL gts, first-max tie-break (strict >)
        float best = -1.0f;
        int   bi   = 0;
        for (int i = 0; i < NGT; ++i) {
            float iou = iou_f(gbox[i], p);
            if (iou > best) { best = iou; bi = i; }
        }
        g = bi;
    }
    assigned_gt[idx] = g;

    if (g >= 0) {
        float iou = iou_f(gbox[g], p);
        float s   = pred_scores[((size_t)b * LL + j) * CC + glab[g]];
        float i2  = iou * iou;
        float al  = s * (i2 * i2 * i2);
        align_anchor[idx] = al;
        atomicMax(max_metric + b * NGT + g, __float_as_uint(al));
        atomicMax(max_iou    + b * NGT + g, __float_as_uint(iou));
    }
}

// ---------------- Kernel E: outputs (full coalesced score write) -----------
__global__ __launch_bounds__(256) void output_kernel(
    const float4* __restrict__ gt_bboxes,
    const int*    __restrict__ gt_labels,
    const int*    __restrict__ assigned_gt,
    const float*  __restrict__ align_anchor,
    const unsigned* __restrict__ max_metric,
    const unsigned* __restrict__ max_iou,
    float*  __restrict__ out_labels,
    float4* __restrict__ out_bboxes,
    float*  __restrict__ out_scores)
{
    int t = blockIdx.x * 256 + threadIdx.x;   // global anchor index
    __shared__ int   s_lab[256];
    __shared__ float s_f[256];

    int label = CC;
    float f = 0.0f;
    if (t < BB * LL) {
        int b = t / LL;
        int g = assigned_gt[t];
        float4 bb;
        if (g >= 0) {
            label = gt_labels[b * NGT + g];
            bb    = gt_bboxes[b * NGT + g];
            float mm = __uint_as_float(max_metric[b * NGT + g]);
            float mi = __uint_as_float(max_iou[b * NGT + g]);
            f = align_anchor[t] / (mm + FEPS) * mi;
        } else {
            bb = gt_bboxes[b * NGT + 0];   // argmax of all-zero mask -> gt 0
        }
        out_labels[t] = (float)label;
        out_bboxes[t] = bb;
    }
    s_lab[threadIdx.x] = label;
    s_f[threadIdx.x]   = f;
    __syncthreads();

    // 256 anchors * 80 classes = 5120 float4, contiguous & coalesced.
    float4* outs = (float4*)(out_scores + (size_t)blockIdx.x * 256 * CC);
    for (int i = threadIdx.x; i < 256 * CC / 4; i += 256) {
        int anchor = i / (CC / 4);
        int c4     = i % (CC / 4);
        int lab    = s_lab[anchor];
        float4 v = {0.f, 0.f, 0.f, 0.f};
        int rel = lab - c4 * 4;
        if (rel >= 0 && rel < 4) ((float*)&v)[rel] = s_f[anchor];
        outs[i] = v;
    }
}

extern "C" void kernel_launch(void* const* d_in, const int* in_sizes, int n_in,
                              void* d_out, int out_size, void* d_ws, size_t ws_size,
                              hipStream_t stream)
{
    const float*  pred_scores = (const float*)d_in[0];
    const float4* pred_bboxes = (const float4*)d_in[1];
    const float2* anchors     = (const float2*)d_in[2];
    const int*    gt_labels   = (const int*)d_in[3];
    const float4* gt_bboxes   = (const float4*)d_in[4];
    // d_in[5] = pad_gt_mask (all ones by construction)

    char* w = (char*)d_ws;
    // zeroed region (one memset): claim_count, claimant, max_metric, max_iou
    int*      claim_count  = (int*)(w);                 // B*L      = 537600 B
    int*      claimant     = (int*)(w + 537600);        // B*L      = 537600 B
    unsigned* max_metric   = (unsigned*)(w + 1075200);  // B*NGT    =   8192 B
    unsigned* max_iou      = (unsigned*)(w + 1083392);  // B*NGT    =   8192 B
    // non-zeroed (fully overwritten or guarded):
    int*      assigned_gt  = (int*)(w + 1091584);       // B*L      = 537600 B
    float*    align_anchor = (float*)(w + 1629184);     // B*L      = 537600 B

    float*  out        = (float*)d_out;
    float*  out_labels = out;                                   // B*L
    float4* out_bboxes = (float4*)(out + (size_t)BB * LL);      // B*L*4
    float*  out_scores = out + (size_t)BB * LL * 5;             // B*L*80

    hipMemsetAsync(w, 0, 1091584, stream);

    topk_kernel<<<BB * NGT, 256, 0, stream>>>(
        pred_scores, pred_bboxes, anchors, gt_labels, gt_bboxes,
        claim_count, claimant);

    dim3 gridC((LL + 255) / 256, BB);
    resolve_kernel<<<gridC, 256, 0, stream>>>(
        pred_scores, pred_bboxes, gt_labels, gt_bboxes,
        claim_count, claimant, assigned_gt, align_anchor, max_metric, max_iou);

    output_kernel<<<(BB * LL + 255) / 256, 256, 0, stream>>>(
        gt_bboxes, gt_labels, assigned_gt, align_anchor, max_metric, max_iou,
        out_labels, out_bboxes, out_scores);
}

// Round 5
// 100.686 us; speedup vs baseline: 1.7641x; 1.1322x over previous
//
#include <hip/hip_runtime.h>
#include <stdint.h>

#define BB   16
#define NGT  128
#define LL   8400
#define CC   80
#define KTOP 13
#define CAP  2048
#define FEPS 1e-9f

typedef float vfloat4 __attribute__((ext_vector_type(4)));

__device__ __forceinline__ float iou_f(float4 g, float4 p) {
    float ix0 = fmaxf(g.x, p.x);
    float iy0 = fmaxf(g.y, p.y);
    float ix1 = fminf(g.z, p.z);
    float iy1 = fminf(g.w, p.w);
    float ow = fmaxf(ix1 - ix0, 0.0f);
    float oh = fmaxf(iy1 - iy0, 0.0f);
    float ov = ow * oh;
    float a1 = fmaxf(g.z - g.x, 0.0f) * fmaxf(g.w - g.y, 0.0f);
    float a2 = fmaxf(p.z - p.x, 0.0f) * fmaxf(p.w - p.y, 0.0f);
    return ov / (a1 + a2 - ov + FEPS);
}

// --------- Kernel A: exact top-13 per (b,gt) row + fused claim -------------
// Phase 1: compact in-box anchor indices to LDS (pure VALU, no gathers).
// Phase 2: bbox gather (L2-resident) + iou; score gather ONLY if iou>0
//          (iou==0 -> metric is exactly 0.0 in the reference, key = ~j).
// Key = (metric_bits << 32) | ~j  -> max-order == (value desc, index asc),
// exactly jax.lax.top_k tie semantics. Zero-fill slots are covered by the
// in-box zero-iou candidates plus virtual zero keys for outside-box j<64.
__global__ __launch_bounds__(256) void topk_kernel(
    const float*  __restrict__ pred_scores,   // B,L,C
    const float4* __restrict__ pred_bboxes,   // B,L
    const float2* __restrict__ anchors,       // L
    const int*    __restrict__ gt_labels,     // B,n
    const float4* __restrict__ gt_bboxes,     // B,n
    int* __restrict__ claim_count,            // B,L (zeroed)
    int* __restrict__ claimant)               // B,L (zeroed)
{
    int row  = blockIdx.x;           // b*NGT + i
    int b    = row >> 7;
    int tid  = threadIdx.x;
    int wave = tid >> 6;
    int lane = tid & 63;

    float4 g   = gt_bboxes[row];
    int label  = gt_labels[row];
    const float*  sc = pred_scores + (size_t)b * LL * CC + label;
    const float4* pb = pred_bboxes + (size_t)b * LL;

    __shared__ int s_cnt;
    __shared__ int s_list[CAP];
    __shared__ unsigned long long wkeys[4 * KTOP];
    __shared__ int s_pick[KTOP];
    if (tid == 0) s_cnt = 0;
    __syncthreads();

    // ---- Phase 1: in-box compaction (wave-aggregated append) ----
    for (int j = tid; j < LL; j += 256) {
        float2 ap = anchors[j];
        float d = fminf(fminf(ap.x - g.x, ap.y - g.y),
                        fminf(g.z - ap.x, g.w - ap.y));
        bool inside = d > FEPS;
        unsigned long long mask = __ballot(inside);
        if (mask) {
            int leader = __ffsll((unsigned long long)mask) - 1;
            int base = 0;
            if (lane == leader) base = atomicAdd(&s_cnt, __popcll(mask));
            base = __shfl(base, leader, 64);
            if (inside) {
                int slot = base + __popcll(mask & ((1ull << lane) - 1ull));
                if (slot < CAP) s_list[slot] = j;
            }
        }
    }
    __syncthreads();
    int c = s_cnt; if (c > CAP) c = CAP;

    // ---- Phase 2: per-lane top-13 over candidates (+ virtual zeros) ----
    unsigned long long keys[KTOP];
#pragma unroll
    for (int k = 0; k < KTOP; ++k) keys[k] = 0ull;

    if (tid < 64) {   // virtual zero-metric keys for outside-box j<64
        float2 ap = anchors[tid];
        float d = fminf(fminf(ap.x - g.x, ap.y - g.y),
                        fminf(g.z - ap.x, g.w - ap.y));
        if (!(d > FEPS)) keys[0] = (unsigned)(~(unsigned)tid);
    }

    for (int t = tid; t < c; t += 256) {
        int j = s_list[t];
        float4 p  = pb[j];                       // L2-resident gather
        float iou = iou_f(g, p);
        unsigned long long key = (unsigned)(~(unsigned)j);
        if (iou > 0.0f) {                        // rare (~10%): HBM gather
            float s   = sc[(size_t)j * CC];
            float i2  = iou * iou;
            float metric = s * (i2 * i2 * i2);
            key |= ((unsigned long long)__float_as_uint(metric) << 32);
        }
        if (key > keys[KTOP - 1]) {
            keys[KTOP - 1] = key;
#pragma unroll
            for (int k = KTOP - 1; k > 0; --k) {
                unsigned long long a = keys[k - 1], cc2 = keys[k];
                keys[k - 1] = (cc2 > a) ? cc2 : a;
                keys[k]     = (cc2 > a) ? a : cc2;
            }
        }
    }

    // Stage 1: per-wave top-13 (13 rounds of wave-argmax + owner-pop).
    for (int r = 0; r < KTOP; ++r) {
        unsigned long long head = keys[0];
        unsigned long long m = head;
#pragma unroll
        for (int off = 1; off < 64; off <<= 1) {
            unsigned long long o = __shfl_xor(m, off, 64);
            if (o > m) m = o;
        }
        if (head == m && m != 0ull) {   // unique owner (keys distinct)
#pragma unroll
            for (int k = 0; k < KTOP - 1; ++k) keys[k] = keys[k + 1];
            keys[KTOP - 1] = 0ull;
        }
        if (lane == 0) wkeys[wave * KTOP + r] = m;
    }
    __syncthreads();

    // Stage 2: wave 0 merges the 4 sorted 13-lists (52 keys, one per lane).
    if (wave == 0) {
        unsigned long long k1 = (lane < 4 * KTOP) ? wkeys[lane] : 0ull;
        for (int r = 0; r < KTOP; ++r) {
            unsigned long long m = k1;
#pragma unroll
            for (int off = 1; off < 64; off <<= 1) {
                unsigned long long o = __shfl_xor(m, off, 64);
                if (o > m) m = o;
            }
            if (k1 == m && m != 0ull) k1 = 0ull;   // pop
            if (lane == 0) s_pick[r] = (int)(~(unsigned)(m & 0xFFFFFFFFull));
        }
    }
    __syncthreads();

    // Fused claim: recheck in-box per pick, scatter atomics.
    if (tid < KTOP) {
        int j = s_pick[tid];
        float2 ap = anchors[j];
        float d = fminf(fminf(ap.x - g.x, ap.y - g.y),
                        fminf(g.z - ap.x, g.w - ap.y));
        if (d > FEPS) {
            atomicAdd(claim_count + b * LL + j, 1);
            atomicMax(claimant + b * LL + j, row & (NGT - 1));
        }
    }
}

// ------- Kernel C: resolve contested + per-GT maxes + labels/bboxes --------
__global__ __launch_bounds__(256) void resolve_kernel(
    const float*  __restrict__ pred_scores,
    const float4* __restrict__ pred_bboxes,
    const int*    __restrict__ gt_labels,
    const float4* __restrict__ gt_bboxes,
    const int*    __restrict__ claim_count,
    const int*    __restrict__ claimant,
    int*      __restrict__ assigned_gt,
    float*    __restrict__ align_anchor,
    unsigned* __restrict__ max_metric,
    unsigned* __restrict__ max_iou,
    float*    __restrict__ out_labels,
    float4*   __restrict__ out_bboxes)
{
    int b = blockIdx.y;
    int j = blockIdx.x * 256 + threadIdx.x;

    __shared__ float4 gbox[NGT];
    __shared__ int    glab[NGT];
    if (threadIdx.x < NGT) {
        gbox[threadIdx.x] = gt_bboxes[b * NGT + threadIdx.x];
        glab[threadIdx.x] = gt_labels[b * NGT + threadIdx.x];
    }
    __syncthreads();
    if (j >= LL) return;

    int idx = b * LL + j;
    int cnt = claim_count[idx];
    int g = -1;
    float4 p = pred_bboxes[(size_t)b * LL + j];

    if (cnt == 1) {
        g = claimant[idx];
    } else if (cnt > 1) {
        // argmax_i iou over ALL gts, first-max tie-break (strict >)
        float best = -1.0f;
        int   bi   = 0;
        for (int i = 0; i < NGT; ++i) {
            float iou = iou_f(gbox[i], p);
            if (iou > best) { best = iou; bi = i; }
        }
        g = bi;
    }
    assigned_gt[idx] = g;

    int label; float4 bb;
    if (g >= 0) {
        float iou = iou_f(gbox[g], p);
        float s   = pred_scores[((size_t)b * LL + j) * CC + glab[g]];
        float i2  = iou * iou;
        float al  = s * (i2 * i2 * i2);
        align_anchor[idx] = al;
        atomicMax(max_metric + b * NGT + g, __float_as_uint(al));
        atomicMax(max_iou    + b * NGT + g, __float_as_uint(iou));
        label = glab[g];
        bb    = gbox[g];
    } else {
        label = CC;          // 80 = NUM_CLASSES
        bb    = gbox[0];     // argmax of all-zero mask -> gt 0
    }
    out_labels[idx] = (float)label;
    out_bboxes[idx] = bb;
}

// ---------------- Kernel E: scores (full coalesced tile write) -------------
__global__ __launch_bounds__(256) void score_kernel(
    const int*    __restrict__ gt_labels,
    const int*    __restrict__ assigned_gt,
    const float*  __restrict__ align_anchor,
    const unsigned* __restrict__ max_metric,
    const unsigned* __restrict__ max_iou,
    float*  __restrict__ out_scores)
{
    int t = blockIdx.x * 256 + threadIdx.x;   // global anchor index (exact)
    __shared__ int   s_lab[256];
    __shared__ float s_f[256];

    int b = t / LL;
    int g = assigned_gt[t];
    int label = CC;
    float f = 0.0f;
    if (g >= 0) {
        label = gt_labels[b * NGT + g];
        float mm = __uint_as_float(max_metric[b * NGT + g]);
        float mi = __uint_as_float(max_iou[b * NGT + g]);
        f = align_anchor[t] / (mm + FEPS) * mi;
    }
    s_lab[threadIdx.x] = label;
    s_f[threadIdx.x]   = f;
    __syncthreads();

    // 256 anchors * 80 classes = 5120 float4, contiguous & coalesced.
    vfloat4* outs = (vfloat4*)(out_scores + (size_t)blockIdx.x * 256 * CC);
    for (int i = threadIdx.x; i < 256 * CC / 4; i += 256) {
        int anchor = i / (CC / 4);
        int c4     = i % (CC / 4);
        int lab    = s_lab[anchor];
        vfloat4 v = {0.f, 0.f, 0.f, 0.f};
        int rel = lab - c4 * 4;
        if (rel >= 0 && rel < 4) v[rel] = s_f[anchor];
        __builtin_nontemporal_store(v, outs + i);
    }
}

extern "C" void kernel_launch(void* const* d_in, const int* in_sizes, int n_in,
                              void* d_out, int out_size, void* d_ws, size_t ws_size,
                              hipStream_t stream)
{
    const float*  pred_scores = (const float*)d_in[0];
    const float4* pred_bboxes = (const float4*)d_in[1];
    const float2* anchors     = (const float2*)d_in[2];
    const int*    gt_labels   = (const int*)d_in[3];
    const float4* gt_bboxes   = (const float4*)d_in[4];
    // d_in[5] = pad_gt_mask (all ones by construction)

    char* w = (char*)d_ws;
    // zeroed region (one memset): claim_count, claimant, max_metric, max_iou
    int*      claim_count  = (int*)(w);                 // B*L      = 537600 B
    int*      claimant     = (int*)(w + 537600);        // B*L      = 537600 B
    unsigned* max_metric   = (unsigned*)(w + 1075200);  // B*NGT    =   8192 B
    unsigned* max_iou      = (unsigned*)(w + 1083392);  // B*NGT    =   8192 B
    // non-zeroed (fully overwritten before read):
    int*      assigned_gt  = (int*)(w + 1091584);       // B*L      = 537600 B
    float*    align_anchor = (float*)(w + 1629184);     // B*L      = 537600 B

    float*  out        = (float*)d_out;
    float*  out_labels = out;                                   // B*L
    float4* out_bboxes = (float4*)(out + (size_t)BB * LL);      // B*L*4
    float*  out_scores = out + (size_t)BB * LL * 5;             // B*L*80

    (void)hipMemsetAsync(w, 0, 1091584, stream);

    topk_kernel<<<BB * NGT, 256, 0, stream>>>(
        pred_scores, pred_bboxes, anchors, gt_labels, gt_bboxes,
        claim_count, claimant);

    dim3 gridC((LL + 255) / 256, BB);
    resolve_kernel<<<gridC, 256, 0, stream>>>(
        pred_scores, pred_bboxes, gt_labels, gt_bboxes,
        claim_count, claimant, assigned_gt, align_anchor, max_metric, max_iou,
        out_labels, out_bboxes);

    score_kernel<<<(BB * LL) / 256, 256, 0, stream>>>(
        gt_labels, assigned_gt, align_anchor, max_metric, max_iou, out_scores);
}

// Round 6
// 96.897 us; speedup vs baseline: 1.8331x; 1.0391x over previous
//
#include <hip/hip_runtime.h>
#include <stdint.h>

#define BB   16
#define NGT  128
#define LL   8400
#define CC   80
#define KTOP 13
#define FEPS 1e-9f

typedef float vfloat4 __attribute__((ext_vector_type(4)));

__device__ __forceinline__ float iou_f(float4 g, float4 p) {
    float ix0 = fmaxf(g.x, p.x);
    float iy0 = fmaxf(g.y, p.y);
    float ix1 = fminf(g.z, p.z);
    float iy1 = fminf(g.w, p.w);
    float ow = fmaxf(ix1 - ix0, 0.0f);
    float oh = fmaxf(iy1 - iy0, 0.0f);
    float ov = ow * oh;
    float a1 = fmaxf(g.z - g.x, 0.0f) * fmaxf(g.w - g.y, 0.0f);
    float a2 = fmaxf(p.z - p.x, 0.0f) * fmaxf(p.w - p.y, 0.0f);
    return ov / (a1 + a2 - ov + FEPS);
}

// --------- Kernel A: exact top-13 per (b,gt) row + fused claim -------------
// ONE WAVE per row, 4 independent waves per block. No LDS, no syncthreads.
// Phase 1: pure-VALU scan of j = lane + 64*it; inside-bits -> 3 reg u64 masks.
// Phase 2: walk own set bits; bbox gather (L2) + iou; score gather only if
//          iou>0 (iou==0 -> metric exactly 0.0 in reference); 13-deep insert.
// Merge:   13 rounds of wave argmax + owner-pop; lane 0 fires claim atomics.
// Key = (metric_bits << 32) | ~j -> max-order == (value desc, index asc),
// exactly jax.lax.top_k tie semantics. Zero-fill slots covered by in-box
// zero-iou candidates plus a virtual zero key ~lane when j=lane is outside.
__global__ __launch_bounds__(256) void topk_kernel(
    const float*  __restrict__ pred_scores,   // B,L,C
    const float4* __restrict__ pred_bboxes,   // B,L
    const float2* __restrict__ anchors,       // L
    const int*    __restrict__ gt_labels,     // B,n
    const float4* __restrict__ gt_bboxes,     // B,n
    int* __restrict__ claim_count,            // B,L (zeroed)
    int* __restrict__ claimant)               // B,L (zeroed)
{
    int wave = threadIdx.x >> 6;
    int lane = threadIdx.x & 63;
    int row  = blockIdx.x * 4 + wave;         // b*NGT + i
    int b    = row >> 7;
    int i_gt = row & (NGT - 1);

    float4 g  = gt_bboxes[row];
    int label = gt_labels[row];
    const float*  sc = pred_scores + (size_t)b * LL * CC + label;
    const float4* pb = pred_bboxes + (size_t)b * LL;

    // ---- Phase 1: pure-VALU in-box scan into register bitmasks ----
    unsigned long long m0 = 0ull, m1 = 0ull, m2 = 0ull;
#pragma unroll 8
    for (int it = 0; it < 64; ++it) {
        int j = lane + (it << 6);
        float2 ap = anchors[j];
        float d = fminf(fminf(ap.x - g.x, ap.y - g.y),
                        fminf(g.z - ap.x, g.w - ap.y));
        m0 |= ((unsigned long long)(d > FEPS)) << it;
    }
#pragma unroll 8
    for (int it = 0; it < 64; ++it) {
        int j = lane + ((it + 64) << 6);
        float2 ap = anchors[j];
        float d = fminf(fminf(ap.x - g.x, ap.y - g.y),
                        fminf(g.z - ap.x, g.w - ap.y));
        m1 |= ((unsigned long long)(d > FEPS)) << it;
    }
#pragma unroll
    for (int it = 0; it < 4; ++it) {
        int j = lane + ((it + 128) << 6);
        if (j < LL) {
            float2 ap = anchors[j];
            float d = fminf(fminf(ap.x - g.x, ap.y - g.y),
                            fminf(g.z - ap.x, g.w - ap.y));
            m2 |= ((unsigned long long)(d > FEPS)) << it;
        }
    }

    // ---- Phase 2: per-lane top-13 over own candidates ----
    unsigned long long keys[KTOP];
#pragma unroll
    for (int k = 0; k < KTOP; ++k) keys[k] = 0ull;

    // virtual zero-metric key for j = lane (< 64) when outside the box
    if (!(m0 & 1ull)) keys[0] = (unsigned)(~(unsigned)lane);

#pragma unroll
    for (int w = 0; w < 3; ++w) {
        unsigned long long mask = (w == 0) ? m0 : (w == 1) ? m1 : m2;
        int itbase = w << 6;
        while (mask) {
            int p = __ffsll(mask) - 1;
            mask &= mask - 1ull;
            int j = lane + ((itbase + p) << 6);
            float4 pbx = pb[j];                      // L2-resident gather
            float iou = iou_f(g, pbx);
            unsigned long long key = (unsigned)(~(unsigned)j);
            if (iou > 0.0f) {                        // rare: score gather
                float s  = sc[(size_t)j * CC];
                float i2 = iou * iou;
                key |= ((unsigned long long)__float_as_uint(s * (i2 * i2 * i2)) << 32);
            }
            if (key > keys[KTOP - 1]) {
                keys[KTOP - 1] = key;
#pragma unroll
                for (int k = KTOP - 1; k > 0; --k) {
                    unsigned long long a = keys[k - 1], c2 = keys[k];
                    keys[k - 1] = (c2 > a) ? c2 : a;
                    keys[k]     = (c2 > a) ? a : c2;
                }
            }
        }
    }

    // ---- Merge: 13 rounds wave-argmax + owner-pop; lane 0 claims ----
    int base = b * LL;
    for (int r = 0; r < KTOP; ++r) {
        unsigned long long head = keys[0];
        unsigned long long m = head;
#pragma unroll
        for (int off = 1; off < 64; off <<= 1) {
            unsigned long long o = __shfl_xor(m, off, 64);
            if (o > m) m = o;
        }
        if (head == m && m != 0ull) {   // unique owner (keys distinct)
#pragma unroll
            for (int k = 0; k < KTOP - 1; ++k) keys[k] = keys[k + 1];
            keys[KTOP - 1] = 0ull;
        }
        if (lane == 0 && m != 0ull) {
            int j = (int)(~(unsigned)(m & 0xFFFFFFFFull));
            float2 ap = anchors[j];
            float d = fminf(fminf(ap.x - g.x, ap.y - g.y),
                            fminf(g.z - ap.x, g.w - ap.y));
            if (d > FEPS) {
                atomicAdd(claim_count + base + j, 1);
                atomicMax(claimant + base + j, i_gt);
            }
        }
    }
}

// ------- Kernel C: resolve contested + per-GT maxes + labels/bboxes --------
__global__ __launch_bounds__(256) void resolve_kernel(
    const float*  __restrict__ pred_scores,
    const float4* __restrict__ pred_bboxes,
    const int*    __restrict__ gt_labels,
    const float4* __restrict__ gt_bboxes,
    const int*    __restrict__ claim_count,
    const int*    __restrict__ claimant,
    int*      __restrict__ assigned_gt,
    float*    __restrict__ align_anchor,
    unsigned* __restrict__ max_metric,
    unsigned* __restrict__ max_iou,
    float*    __restrict__ out_labels,
    float4*   __restrict__ out_bboxes)
{
    int b = blockIdx.y;
    int j = blockIdx.x * 256 + threadIdx.x;

    __shared__ float4 gbox[NGT];
    __shared__ int    glab[NGT];
    if (threadIdx.x < NGT) {
        gbox[threadIdx.x] = gt_bboxes[b * NGT + threadIdx.x];
        glab[threadIdx.x] = gt_labels[b * NGT + threadIdx.x];
    }
    __syncthreads();
    if (j >= LL) return;

    int idx = b * LL + j;
    int cnt = claim_count[idx];
    int g = -1;
    float4 p = pred_bboxes[(size_t)b * LL + j];

    if (cnt == 1) {
        g = claimant[idx];
    } else if (cnt > 1) {
        // argmax_i iou over ALL gts, first-max tie-break (strict >)
        float best = -1.0f;
        int   bi   = 0;
        for (int i = 0; i < NGT; ++i) {
            float iou = iou_f(gbox[i], p);
            if (iou > best) { best = iou; bi = i; }
        }
        g = bi;
    }
    assigned_gt[idx] = g;

    int label; float4 bb;
    if (g >= 0) {
        float iou = iou_f(gbox[g], p);
        float s   = pred_scores[((size_t)b * LL + j) * CC + glab[g]];
        float i2  = iou * iou;
        float al  = s * (i2 * i2 * i2);
        align_anchor[idx] = al;
        atomicMax(max_metric + b * NGT + g, __float_as_uint(al));
        atomicMax(max_iou    + b * NGT + g, __float_as_uint(iou));
        label = glab[g];
        bb    = gbox[g];
    } else {
        label = CC;          // 80 = NUM_CLASSES
        bb    = gbox[0];     // argmax of all-zero mask -> gt 0
    }
    out_labels[idx] = (float)label;
    out_bboxes[idx] = bb;
}

// ---------------- Kernel E: scores (full coalesced tile write) -------------
__global__ __launch_bounds__(256) void score_kernel(
    const int*    __restrict__ gt_labels,
    const int*    __restrict__ assigned_gt,
    const float*  __restrict__ align_anchor,
    const unsigned* __restrict__ max_metric,
    const unsigned* __restrict__ max_iou,
    float*  __restrict__ out_scores)
{
    int t = blockIdx.x * 256 + threadIdx.x;   // global anchor index (exact)
    __shared__ int   s_lab[256];
    __shared__ float s_f[256];

    int b = t / LL;
    int g = assigned_gt[t];
    int label = CC;
    float f = 0.0f;
    if (g >= 0) {
        label = gt_labels[b * NGT + g];
        float mm = __uint_as_float(max_metric[b * NGT + g]);
        float mi = __uint_as_float(max_iou[b * NGT + g]);
        f = align_anchor[t] / (mm + FEPS) * mi;
    }
    s_lab[threadIdx.x] = label;
    s_f[threadIdx.x]   = f;
    __syncthreads();

    // 256 anchors * 80 classes = 5120 float4, contiguous & coalesced.
    vfloat4* outs = (vfloat4*)(out_scores + (size_t)blockIdx.x * 256 * CC);
    for (int i = threadIdx.x; i < 256 * CC / 4; i += 256) {
        int anchor = i / (CC / 4);
        int c4     = i % (CC / 4);
        int lab    = s_lab[anchor];
        vfloat4 v = {0.f, 0.f, 0.f, 0.f};
        int rel = lab - c4 * 4;
        if (rel >= 0 && rel < 4) v[rel] = s_f[anchor];
        __builtin_nontemporal_store(v, outs + i);
    }
}

extern "C" void kernel_launch(void* const* d_in, const int* in_sizes, int n_in,
                              void* d_out, int out_size, void* d_ws, size_t ws_size,
                              hipStream_t stream)
{
    const float*  pred_scores = (const float*)d_in[0];
    const float4* pred_bboxes = (const float4*)d_in[1];
    const float2* anchors     = (const float2*)d_in[2];
    const int*    gt_labels   = (const int*)d_in[3];
    const float4* gt_bboxes   = (const float4*)d_in[4];
    // d_in[5] = pad_gt_mask (all ones by construction)

    char* w = (char*)d_ws;
    // zeroed region (one memset): claim_count, claimant, max_metric, max_iou
    int*      claim_count  = (int*)(w);                 // B*L      = 537600 B
    int*      claimant     = (int*)(w + 537600);        // B*L      = 537600 B
    unsigned* max_metric   = (unsigned*)(w + 1075200);  // B*NGT    =   8192 B
    unsigned* max_iou      = (unsigned*)(w + 1083392);  // B*NGT    =   8192 B
    // non-zeroed (fully overwritten before read):
    int*      assigned_gt  = (int*)(w + 1091584);       // B*L      = 537600 B
    float*    align_anchor = (float*)(w + 1629184);     // B*L      = 537600 B

    float*  out        = (float*)d_out;
    float*  out_labels = out;                                   // B*L
    float4* out_bboxes = (float4*)(out + (size_t)BB * LL);      // B*L*4
    float*  out_scores = out + (size_t)BB * LL * 5;             // B*L*80

    (void)hipMemsetAsync(w, 0, 1091584, stream);

    topk_kernel<<<BB * NGT / 4, 256, 0, stream>>>(
        pred_scores, pred_bboxes, anchors, gt_labels, gt_bboxes,
        claim_count, claimant);

    dim3 gridC((LL + 255) / 256, BB);
    resolve_kernel<<<gridC, 256, 0, stream>>>(
        pred_scores, pred_bboxes, gt_labels, gt_bboxes,
        claim_count, claimant, assigned_gt, align_anchor, max_metric, max_iou,
        out_labels, out_bboxes);

    score_kernel<<<(BB * LL) / 256, 256, 0, stream>>>(
        gt_labels, assigned_gt, align_anchor, max_metric, max_iou, out_scores);
}